// Round 5
// baseline (317.603 us; speedup 1.0000x reference)
//
#include <hip/hip_runtime.h>
#include <hip/hip_bf16.h>
#include <stdint.h>

// GatheringLoss: score = q[32768x512] @ items[4096x512]^T, idx = argmax_row,
// out = mean((q - items[idx])^2).
// R5: cut staged volume (R4 was L3/L2-BW-bound: 1GB staged @ ~4TB/s).
//  - BM=128: A (q tile) resident in LDS for FULL K=512 (128KB, staged once,
//    XOR-swizzled) -> A traffic 512MB -> 32MB.
//  - B (items, 4MB total = one XCD L2) streamed as 128x32 chunks (8KB),
//    3-buffer / stage-2-ahead / counted vmcnt(1), ONE barrier per chunk.
//  - per-lane running argmax folded at each col-tile end (no shfl/LDS until
//    block epilogue); no col-split -> idx written directly, no merge pass.
//
// ws: [0,32MB) q_fp16 | [+4MB) items_fp16 | [+128KB) idx[32768] i32
//     | [+1KB) partials[256]

#define D_DIM 512
#define M_ITEMS 4096
#define N_ROWS 32768
#define BM 128
#define BN 128
#define BKC 32               // K per chunk
#define NCH (D_DIM / BKC)    // 16 chunks per col-tile
#define NCT (M_ITEMS / BN)   // 32 col-tiles
#define TOTCH (NCT * NCH)    // 512 chunks
#define MROWS 128

typedef _Float16 half8 __attribute__((ext_vector_type(8)));
typedef _Float16 half4h __attribute__((ext_vector_type(4)));
typedef float f32x4 __attribute__((ext_vector_type(4)));

#define GLD_LDS16(g, l)                                                        \
  __builtin_amdgcn_global_load_lds(                                            \
      (__attribute__((address_space(1))) const void*)(g),                      \
      (__attribute__((address_space(3))) void*)(l), 16, 0, 0)

#define BAR() __builtin_amdgcn_s_barrier()
#define SCHEDB() __builtin_amdgcn_sched_barrier(0)
#define VMW0() asm volatile("s_waitcnt vmcnt(0)" ::: "memory")
#define VMW1() asm volatile("s_waitcnt vmcnt(1)" ::: "memory")

__global__ __launch_bounds__(256) void cast_f32_f16(
    const float* __restrict__ in, _Float16* __restrict__ out, int n4) {
  const int stride = gridDim.x * blockDim.x;
  for (int i = blockIdx.x * blockDim.x + threadIdx.x; i < n4; i += stride) {
    const float4 v = reinterpret_cast<const float4*>(in)[i];
    half4h h;
    h.x = (_Float16)v.x;
    h.y = (_Float16)v.y;
    h.z = (_Float16)v.z;
    h.w = (_Float16)v.w;
    reinterpret_cast<half4h*>(out)[i] = h;
  }
}

// Stage B chunk J into Blds[buf]: 512 threads x 1 x 16B = 8KB.
// LDS (col, sl) holds global k-slot sl ^ ((col>>1)&3); col=t>>2, sl=t&3.
#define STAGE_B(J, buf)                                                        \
  do {                                                                         \
    const int colJ_ = ((J) >> 4) * BN + (t >> 2);                              \
    const int cJ_ = ((J) & (NCH - 1)) * BKC;                                   \
    const int sJ_ = ((t & 3) ^ ((t >> 3) & 3)) * 8;                            \
    GLD_LDS16(ih + (size_t)colJ_ * D_DIM + cJ_ + sJ_, &Blds[buf][0] + t * 8);  \
  } while (0)

__global__ __launch_bounds__(512, 2) void score_argmax(
    const _Float16* __restrict__ qh, const _Float16* __restrict__ ih,
    int* __restrict__ idxArr) {
  __shared__ _Float16 Alds[BM * D_DIM];  // 128 KiB, swizzled full-K A
  __shared__ _Float16 Blds[3][BN * BKC]; // 24 KiB, rotating B chunks
  __shared__ float sV[4][BM];            // 2 KiB
  __shared__ int sI[4][BM];              // 2 KiB

  const int t = threadIdx.x; // 0..511
  const int lane = t & 63;
  const int wid = t >> 6;  // 0..7
  const int wm = wid >> 2; // 0..1 (row half: 64 rows each)
  const int wn = wid & 3;  // 0..3 (col quarter: 32 cols each)
  const int ln = lane & 15;
  const int lg = lane >> 4; // 0..3

  // T1: XCD chunking (grid 256 = 8 XCD x 32)
  const int bid = blockIdx.x;
  const int rb = (bid & 7) * 32 + (bid >> 3);
  const int row0 = rb * BM;

  // --- prologue: stage A once (16 x 16B/thread = 128KB), swizzled:
  // LDS slot f=(row,s) holds global k-slot s^(row&7).
#pragma unroll
  for (int i = 0; i < 16; ++i) {
    const int f = i * 512 + t;
    const int r = f >> 6;
    const int s = f & 63;
    GLD_LDS16(qh + (size_t)(row0 + r) * D_DIM + ((s ^ (r & 7)) * 8),
              (_Float16*)Alds + (size_t)f * 8);
  }
  STAGE_B(0, 0);
  STAGE_B(1, 1);
  VMW0();
  BAR();

  f32x4 acc[4][2];
#pragma unroll
  for (int fr = 0; fr < 4; ++fr)
#pragma unroll
    for (int fc = 0; fc < 2; ++fc) acc[fr][fc] = (f32x4){0.f, 0.f, 0.f, 0.f};
  float rmax[4][4];
  int ridx[4][4];
#pragma unroll
  for (int a = 0; a < 4; ++a)
#pragma unroll
    for (int b = 0; b < 4; ++b) {
      rmax[a][b] = -3.0e38f;
      ridx[a][b] = 0;
    }

  int rdbuf = 0, stbuf = 2; // read buf = J%3, stage buf = (J+2)%3
#pragma unroll 1
  for (int J = 0; J < TOTCH; ++J) {
    if (J == TOTCH - 1) {
      VMW0();
    } else {
      VMW1(); // oldest outstanding stage (chunk J) landed
    }
    BAR(); // all waves' stages for buf[J%3] landed; prev readers done
    SCHEDB();
    if (J + 2 < TOTCH) STAGE_B(J + 2, stbuf);
    const int c = J & (NCH - 1);
    const _Float16* Bb = &Blds[rdbuf][0];
    half8 af[4], bf[2];
#pragma unroll
    for (int fr = 0; fr < 4; ++fr) {
      const int row = wm * 64 + fr * 16 + ln;
      const int slot = (c * 4 + lg) ^ (ln & 7);
      af[fr] = *(const half8*)(Alds + (size_t)row * D_DIM + slot * 8);
    }
#pragma unroll
    for (int fc = 0; fc < 2; ++fc) {
      const int col = wn * 32 + fc * 16 + ln;
      const int sl = lg ^ ((col >> 1) & 3);
      bf[fc] = *(const half8*)(Bb + (size_t)col * BKC + sl * 8);
    }
#pragma unroll
    for (int fr = 0; fr < 4; ++fr)
#pragma unroll
      for (int fc = 0; fc < 2; ++fc)
        acc[fr][fc] = __builtin_amdgcn_mfma_f32_16x16x32_f16(
            af[fr], bf[fc], acc[fr][fc], 0, 0, 0);

    if (c == NCH - 1) { // col-tile complete: fold into per-lane running max
      const int col0 = (J >> 4) * BN;
#pragma unroll
      for (int fr = 0; fr < 4; ++fr)
#pragma unroll
        for (int r = 0; r < 4; ++r)
#pragma unroll
          for (int fc = 0; fc < 2; ++fc) {
            const float v = acc[fr][fc][r];
            const int cc = col0 + wn * 32 + fc * 16 + ln;
            if (v > rmax[fr][r]) { // cols ascend: strict > keeps lowest idx
              rmax[fr][r] = v;
              ridx[fr][r] = cc;
            }
          }
#pragma unroll
      for (int fr = 0; fr < 4; ++fr)
#pragma unroll
        for (int fc = 0; fc < 2; ++fc)
          acc[fr][fc] = (f32x4){0.f, 0.f, 0.f, 0.f};
    }
    rdbuf = (rdbuf == 2) ? 0 : rdbuf + 1;
    stbuf = (stbuf == 2) ? 0 : stbuf + 1;
  }

  // --- block epilogue: reduce across 16 col-lanes, then across wn waves.
  // C layout: col=lane&15, row=(lane>>4)*4+reg (m89-verified).
#pragma unroll
  for (int fr = 0; fr < 4; ++fr)
#pragma unroll
    for (int r = 0; r < 4; ++r) {
      float v = rmax[fr][r];
      int cidx = ridx[fr][r];
#pragma unroll
      for (int m = 1; m < 16; m <<= 1) {
        const float ov = __shfl_xor(v, m, 64);
        const int oc = __shfl_xor(cidx, m, 64);
        if (ov > v || (ov == v && oc < cidx)) {
          v = ov;
          cidx = oc;
        }
      }
      if (ln == 0) {
        const int row = wm * 64 + fr * 16 + lg * 4 + r;
        sV[wn][row] = v;
        sI[wn][row] = cidx;
      }
    }
  __syncthreads();
  if (t < BM) {
    float bv = sV[0][t];
    int bi = sI[0][t];
#pragma unroll
    for (int w = 1; w < 4; ++w) {
      const float v = sV[w][t];
      const int ii = sI[w][t];
      if (v > bv || (v == bv && ii < bi)) {
        bv = v;
        bi = ii;
      }
    }
    idxArr[row0 + t] = bi;
  }
}

__global__ __launch_bounds__(256) void gather_mse(
    const float* __restrict__ qf, const float* __restrict__ itf,
    const int* __restrict__ idxArr, float* __restrict__ partials) {
  __shared__ float sSum[4];
  const int t = threadIdx.x;
  const int lane = t & 63;
  const int wv = t >> 6;
  const int row0 = blockIdx.x * MROWS;

  float lsum = 0.0f;
  for (int rr = 0; rr < 32; ++rr) {
    const int row = row0 + wv * 32 + rr;
    const int bi = idxArr[row];
    const float* qr = qf + (size_t)row * D_DIM + lane * 8;
    const float* gr = itf + (size_t)bi * D_DIM + lane * 8;
    const float4 a0 = reinterpret_cast<const float4*>(qr)[0];
    const float4 a1 = reinterpret_cast<const float4*>(qr)[1];
    const float4 b0 = reinterpret_cast<const float4*>(gr)[0];
    const float4 b1 = reinterpret_cast<const float4*>(gr)[1];
    const float d0 = a0.x - b0.x, d1 = a0.y - b0.y;
    const float d2 = a0.z - b0.z, d3 = a0.w - b0.w;
    const float d4 = a1.x - b1.x, d5 = a1.y - b1.y;
    const float d6 = a1.z - b1.z, d7 = a1.w - b1.w;
    lsum += d0 * d0 + d1 * d1 + d2 * d2 + d3 * d3 + d4 * d4 + d5 * d5 +
            d6 * d6 + d7 * d7;
  }
#pragma unroll
  for (int m = 1; m < 64; m <<= 1) lsum += __shfl_xor(lsum, m, 64);
  if (lane == 0) sSum[wv] = lsum;
  __syncthreads();
  if (t == 0) partials[blockIdx.x] = sSum[0] + sSum[1] + sSum[2] + sSum[3];
}

__global__ __launch_bounds__(256) void final_reduce(
    const float* __restrict__ partials, float* __restrict__ out) {
  __shared__ float sS[4];
  const int t = threadIdx.x;
  float v = partials[t]; // exactly 256 partials
#pragma unroll
  for (int m = 1; m < 64; m <<= 1) v += __shfl_xor(v, m, 64);
  if ((t & 63) == 0) sS[t >> 6] = v;
  __syncthreads();
  if (t == 0)
    out[0] = (sS[0] + sS[1] + sS[2] + sS[3]) *
             (1.0f / ((float)N_ROWS * (float)D_DIM));
}

extern "C" void kernel_launch(void* const* d_in, const int* in_sizes, int n_in,
                              void* d_out, int out_size, void* d_ws,
                              size_t ws_size, hipStream_t stream) {
  const float* qf = (const float*)d_in[0];  // [32768][512]
  const float* itf = (const float*)d_in[1]; // [4096][512]
  char* ws = (char*)d_ws;
  _Float16* qh = (_Float16*)ws;                                // 32 MB
  _Float16* ih = (_Float16*)(ws + (size_t)N_ROWS * D_DIM * 2); // 4 MB
  char* p = ws + (size_t)N_ROWS * D_DIM * 2 + (size_t)M_ITEMS * D_DIM * 2;
  int* idxArr = (int*)p;                                       // 128 KB
  float* partials = (float*)(p + (size_t)N_ROWS * 4);          // 1 KB
  float* out = (float*)d_out;

  cast_f32_f16<<<2048, 256, 0, stream>>>(qf, qh, N_ROWS * D_DIM / 4);
  cast_f32_f16<<<512, 256, 0, stream>>>(itf, ih, M_ITEMS * D_DIM / 4);
  score_argmax<<<N_ROWS / BM, 512, 0, stream>>>(qh, ih, idxArr);
  gather_mse<<<N_ROWS / MROWS, 256, 0, stream>>>(qf, itf, idxArr, partials);
  final_reduce<<<1, 256, 0, stream>>>(partials, out);
}